// Round 1
// baseline (229.257 us; speedup 1.0000x reference)
//
#include <hip/hip_runtime.h>
#include <hip/hip_bf16.h>

// Head attention: x[4,4096,1024] f32, Wq/Wk/Wv[1024,64] f32 -> out[4,4096,64] f32
// Pipeline: (1) W transpose+cast -> Wt bf16 [192][1024] (q pre-scaled by C^-0.5)
//           (2) MFMA projection  -> q,k,v bf16 [B*T][64]
//           (3) v transpose      -> vT bf16 [B][64][T]
//           (4) flash attention, wave-private 16-row tiles, online softmax

#define BB 4
#define TT 4096
#define CC 1024
#define HH 64
#define N3 192  // 3*H

typedef __attribute__((ext_vector_type(8))) short bf16x8;
typedef __attribute__((ext_vector_type(4))) float f32x4;

__device__ __forceinline__ short f2bf(float f) {
  union { float f; unsigned u; } v; v.f = f;
  unsigned r = v.u + 0x7fffu + ((v.u >> 16) & 1u);  // RNE
  return (short)(r >> 16);
}

// ---------------- Kernel 1: W -> Wt bf16 [192][1024], q-part scaled ----------
__global__ void wt_kernel(const float* __restrict__ Wq, const float* __restrict__ Wk,
                          const float* __restrict__ Wv, short* __restrict__ Wt) {
  int idx = blockIdx.x * 256 + threadIdx.x;
  if (idx >= N3 * CC) return;
  int n  = idx >> 10;      // 0..191
  int kk = idx & 1023;     // contiguous per thread -> coalesced store
  const float* W = (n < HH) ? Wq : ((n < 2 * HH) ? Wk : Wv);
  float val = W[kk * HH + (n & (HH - 1))];
  if (n < HH) val *= 0.03125f;  // C^-0.5 folded into q
  Wt[idx] = f2bf(val);
}

// ---------------- Kernel 2: qkv projection (MFMA 16x16x32 bf16) --------------
// block = 256 thr (4 waves), 64 rows/block; wave w: rows w*16..w*16+15, all 192 cols
__launch_bounds__(256)
__global__ void proj_kernel(const float* __restrict__ x, const short* __restrict__ Wt,
                            short* __restrict__ qo, short* __restrict__ ko,
                            short* __restrict__ vo) {
  int wave = threadIdx.x >> 6, lane = threadIdx.x & 63;
  int l15 = lane & 15, lg = lane >> 4;
  int row0 = blockIdx.x * 64 + wave * 16;
  const float* xr = x + (size_t)(row0 + l15) * CC;

  f32x4 acc[12];
#pragma unroll
  for (int i = 0; i < 12; ++i) acc[i] = (f32x4){0.f, 0.f, 0.f, 0.f};

  for (int ks = 0; ks < CC / 32; ++ks) {
    int k0 = ks * 32 + lg * 8;
    bf16x8 a;
#pragma unroll
    for (int j = 0; j < 8; ++j) a[j] = f2bf(xr[k0 + j]);
#pragma unroll
    for (int nf = 0; nf < 12; ++nf) {
      bf16x8 bfr = *(const bf16x8*)(Wt + (nf * 16 + l15) * CC + k0);
      acc[nf] = __builtin_amdgcn_mfma_f32_16x16x32_bf16(a, bfr, acc[nf], 0, 0, 0);
    }
  }
#pragma unroll
  for (int nf = 0; nf < 12; ++nf) {
    short* dst = (nf < 4) ? qo : (nf < 8 ? ko : vo);
    int h = (nf & 3) * 16 + l15;
#pragma unroll
    for (int reg = 0; reg < 4; ++reg) {
      int r = row0 + lg * 4 + reg;
      dst[(size_t)r * HH + h] = f2bf(acc[nf][reg]);
    }
  }
}

// ---------------- Kernel 3: v [B*T][64] -> vT [B][64][T] ---------------------
__global__ void vt_kernel(const short* __restrict__ v, short* __restrict__ vT) {
  int idx = blockIdx.x * 256 + threadIdx.x;  // B*H*(T/8) = 131072
  int t8 = idx & (TT / 8 - 1);
  int h  = (idx >> 9) & (HH - 1);
  int b  = idx >> 15;
  bf16x8 r;
#pragma unroll
  for (int j = 0; j < 8; ++j)
    r[j] = v[((size_t)b * TT + t8 * 8 + j) * HH + h];
  *(bf16x8*)(vT + ((size_t)b * HH + h) * TT + t8 * 8) = r;
}

// ---------------- Kernel 4: flash attention ----------------------------------
// grid = B * T/64 blocks, 4 waves/block; wave owns 16 q-rows (no block barriers).
// K/V fragments read directly from global (L2-resident); P goes through
// wave-private XOR-swizzled LDS (breaks the stride-128B 32-way bank conflict).
__launch_bounds__(256)
__global__ void attn_kernel(const short* __restrict__ q, const short* __restrict__ k,
                            const short* __restrict__ vT, float* __restrict__ out) {
  __shared__ __align__(16) short ps[4][16 * 64];
  int wave = threadIdx.x >> 6, lane = threadIdx.x & 63;
  int l15 = lane & 15, lg = lane >> 4;
  int b  = blockIdx.x >> 6;
  int qt = blockIdx.x & 63;
  int row0 = qt * 64 + wave * 16;

  const short* qb = q + ((size_t)b * TT + row0 + l15) * HH;
  bf16x8 qa0 = *(const bf16x8*)(qb + lg * 8);
  bf16x8 qa1 = *(const bf16x8*)(qb + 32 + lg * 8);

  const short* kb = k + (size_t)b * TT * HH;
  const short* vb = vT + (size_t)b * HH * TT;

  f32x4 acc[4];
#pragma unroll
  for (int i = 0; i < 4; ++i) acc[i] = (f32x4){0.f, 0.f, 0.f, 0.f};
  float m4[4] = {-1e30f, -1e30f, -1e30f, -1e30f};
  float l4[4] = {0.f, 0.f, 0.f, 0.f};

  char* psw = (char*)&ps[wave][0];

  for (int kt = 0; kt < TT / 64; ++kt) {
    int s0 = kt * 64;
    // ---- S = q k^T (16x64), 4 col-frags x 2 k-steps ----
    f32x4 s[4];
#pragma unroll
    for (int cf = 0; cf < 4; ++cf) {
      const short* kr = kb + (size_t)(s0 + cf * 16 + l15) * HH + lg * 8;
      bf16x8 k0 = *(const bf16x8*)(kr);
      bf16x8 k1 = *(const bf16x8*)(kr + 32);
      f32x4 t = (f32x4){0.f, 0.f, 0.f, 0.f};
      t = __builtin_amdgcn_mfma_f32_16x16x32_bf16(qa0, k0, t, 0, 0, 0);
      t = __builtin_amdgcn_mfma_f32_16x16x32_bf16(qa1, k1, t, 0, 0, 0);
      s[cf] = t;
    }
    // ---- prefetch V frags (used after softmax; hides L2 latency) ----
    bf16x8 vf[2][4];
#pragma unroll
    for (int ks = 0; ks < 2; ++ks)
#pragma unroll
      for (int hf = 0; hf < 4; ++hf)
        vf[ks][hf] = *(const bf16x8*)(vb + (size_t)(hf * 16 + l15) * TT + s0 + ks * 32 + lg * 8);

    // ---- online softmax (row stats per reg; 16-lane group shuffle reduce) ----
    float scale[4], rsum[4];
#pragma unroll
    for (int reg = 0; reg < 4; ++reg) {
      float mx = fmaxf(fmaxf(s[0][reg], s[1][reg]), fmaxf(s[2][reg], s[3][reg]));
      mx = fmaxf(mx, __shfl_xor(mx, 1));
      mx = fmaxf(mx, __shfl_xor(mx, 2));
      mx = fmaxf(mx, __shfl_xor(mx, 4));
      mx = fmaxf(mx, __shfl_xor(mx, 8));
      float mnew = fmaxf(m4[reg], mx);
      scale[reg] = __expf(m4[reg] - mnew);
      m4[reg] = mnew;
      rsum[reg] = 0.f;
    }
    // p = exp(s - m); write bf16 P tile to swizzled LDS
#pragma unroll
    for (int cf = 0; cf < 4; ++cf) {
#pragma unroll
      for (int reg = 0; reg < 4; ++reg) {
        float p = __expf(s[cf][reg] - m4[reg]);
        rsum[reg] += p;
        int i = lg * 4 + reg;
        int boff = (i * 128 + (cf * 16 + l15) * 2) ^ ((i & 7) << 4);
        *(short*)(psw + boff) = f2bf(p);
      }
    }
#pragma unroll
    for (int reg = 0; reg < 4; ++reg) {
      float r = rsum[reg];
      r += __shfl_xor(r, 1);
      r += __shfl_xor(r, 2);
      r += __shfl_xor(r, 4);
      r += __shfl_xor(r, 8);
      l4[reg] = l4[reg] * scale[reg] + r;
    }
#pragma unroll
    for (int hf = 0; hf < 4; ++hf)
#pragma unroll
      for (int reg = 0; reg < 4; ++reg) acc[hf][reg] *= scale[reg];

    // ---- O += P V ----
#pragma unroll
    for (int ks = 0; ks < 2; ++ks) {
      int boff = (l15 * 128 + ks * 64 + lg * 16) ^ ((l15 & 7) << 4);
      bf16x8 pa = *(const bf16x8*)(psw + boff);
#pragma unroll
      for (int hf = 0; hf < 4; ++hf)
        acc[hf] = __builtin_amdgcn_mfma_f32_16x16x32_bf16(pa, vf[ks][hf], acc[hf], 0, 0, 0);
    }
  }

  // ---- epilogue: O /= l, store f32 ----
#pragma unroll
  for (int reg = 0; reg < 4; ++reg) {
    float inv = 1.0f / l4[reg];
#pragma unroll
    for (int hf = 0; hf < 4; ++hf) {
      int r = row0 + lg * 4 + reg;
      out[((size_t)b * TT + r) * HH + hf * 16 + l15] = acc[hf][reg] * inv;
    }
  }
}

extern "C" void kernel_launch(void* const* d_in, const int* in_sizes, int n_in,
                              void* d_out, int out_size, void* d_ws, size_t ws_size,
                              hipStream_t stream) {
  const float* x  = (const float*)d_in[0];
  const float* Wq = (const float*)d_in[1];
  const float* Wk = (const float*)d_in[2];
  const float* Wv = (const float*)d_in[3];
  float* out = (float*)d_out;

  char* ws = (char*)d_ws;
  short* Wt = (short*)ws;                            // 384 KB
  short* q  = (short*)(ws + 0x80000);                // 2 MB
  short* k  = (short*)(ws + 0x80000 + 0x200000);     // 2 MB
  short* v  = (short*)(ws + 0x80000 + 0x400000);     // 2 MB
  short* vT = (short*)(ws + 0x80000 + 0x600000);     // 2 MB   (total 8.5 MB)

  hipLaunchKernelGGL(wt_kernel,   dim3(768), dim3(256), 0, stream, Wq, Wk, Wv, Wt);
  hipLaunchKernelGGL(proj_kernel, dim3(256), dim3(256), 0, stream, x, Wt, q, k, v);
  hipLaunchKernelGGL(vt_kernel,   dim3(512), dim3(256), 0, stream, v, vT);
  hipLaunchKernelGGL(attn_kernel, dim3(256), dim3(256), 0, stream, q, k, vT, out);
}